// Round 9
// baseline (153.149 us; speedup 1.0000x reference)
//
#include <hip/hip_runtime.h>

// GroupNorm(32) -> phi 1x1 -> soft-VQ softmax vs codebook -> wz 1x1 + residual. fp32 I/O.
// x:(10,64,128,128), mb:(64,512), phi_w/wz_w:(64,64). B=10, C=64, HW=16384, K=512.
//
// R18 = R17 inner structure (16 half-chunks, triple-buffered counted-vmcnt staging)
// with 512-THREAD blocks to buy residency. R17 counters: occupancy 35.6% (LDS-capped
// 4 blocks/CU = 16 waves), VGPR only 52 -> wave slots wasted; per-wave lifetime 43k cy
// vs 6k issue = latency-bound on the per-chunk serial chain.
//  - 8 waves share one Fg (24KB): per wave ONE 1KB global_load_lds per half-chunk
//    (was 2). Sl 20.5KB. Block total 44.5KB -> 3 blocks/CU x 8 waves = 24 waves/CU
//    (6/SIMD, +50% vs R17).
//  - Counted waits re-derived for 1 load/stage: steady vmcnt(1), vmcnt(0) at hc==14.
//    Ledger: inside the loop only stage loads generate vmem (GN/phi loads complete
//    pre-loop; epilogue loads issue post-loop; vmcnt accounting is in-order).
//  - Inner loop / math / ws layout bit-identical to R17 -> absmax unchanged.
//
// ws (ushort): identical to R11/R17:
//  [0    ..32768) mbA  (((hc*2+u)*2+s)*64+lane)*8+j = mb[s*32+q*8+j][(hc*2+u)*16+m]
//  [32768..65536) mbY  ((hc*4+mt)*64+lane)*8+j      = mb[mt*16+m][hc*32+q*8+j]
//  [65536..69632) phiA ((mt*2+s)*64+lane)*8+j = phi_w[mt*16+m][s*32+q*8+j]
//  [69632..73728) wzA  same for wz_w
//  float view at ushort 73728 (statf): [0..320) sum[b*32+g], [320..640) sumsq (atomic)

#define HWN 16384
#define CCH 64
#define PSC 0.18033688011112042f   // 0.125 * log2(e)
#define ETS 40                     // E row stride (ushorts): 32 entries + 8 pad, 16B-mult

using short8 = __attribute__((ext_vector_type(8))) short;
using f32x4  = __attribute__((ext_vector_type(4))) float;

__device__ __forceinline__ ushort f2bf(float f) {
    union { float f; unsigned int i; } v; v.f = f;
    return (ushort)((v.i + 0x8000u) >> 16);   // round-half-up
}
__device__ __forceinline__ unsigned int pk2(float a, float b) {
    union { float f; unsigned int i; } va, vb; va.f = a; vb.f = b;
    return __builtin_amdgcn_perm(vb.i + 0x8000u, va.i + 0x8000u, 0x07060302u);
}

// blocks [0, nstat): GroupNorm partial sums, 8 parts per (b,g), atomicAdd into statf.
// blocks [nstat, nstat+288): weight prep gathers. (unchanged from R11)
__global__ __launch_bounds__(256) void prep_stats_kernel(
    const float* __restrict__ x, const float* __restrict__ mb,
    const float* __restrict__ phiw, const float* __restrict__ wzw,
    ushort* __restrict__ ws, int nstat)
{
    if (blockIdx.x >= nstat) {
        int i = (blockIdx.x - nstat) * 256 + threadIdx.x;   // 0..73727
        int j = i & 7, lane = (i >> 3) & 63, m = lane & 15, q = lane >> 4;
        if (i < 32768) {
            int t = i >> 9, tile = t >> 1, s = t & 1;
            ws[i] = f2bf(mb[(s * 32 + q * 8 + j) * 512 + tile * 16 + m]);
        } else if (i < 65536) {
            int t = (i - 32768) >> 9;
            int mt = t & 3, u2 = t >> 2, s2 = u2 & 1, cc = u2 >> 1;
            ws[i] = f2bf(mb[(mt * 16 + m) * 512 + cc * 64 + s2 * 32 + q * 8 + j]);
        } else if (i < 69632) {
            int t = (i - 65536) >> 9, mt = t >> 1, s = t & 1;
            ws[i] = f2bf(phiw[(mt * 16 + m) * 64 + s * 32 + q * 8 + j]);
        } else {
            int t = (i - 69632) >> 9, mt = t >> 1, s = t & 1;
            ws[i] = f2bf(wzw[(mt * 16 + m) * 64 + s * 32 + q * 8 + j]);
        }
        return;
    }
    float* statf = (float*)(ws + 73728);
    int blk  = blockIdx.x;            // b*256 + g*8 + part
    int b    = blk >> 8;
    int g    = (blk >> 3) & 31;
    int part = blk & 7;
    const float4* b4 = (const float4*)(x + (size_t)b * CCH * HWN + (size_t)(g * 2) * HWN) + part * 1024;
    float s = 0.f, s2 = 0.f;
    for (int i = threadIdx.x; i < 1024; i += 256) {
        float4 u = b4[i];
        s  += (u.x + u.y) + (u.z + u.w);
        s2 += (u.x*u.x + u.y*u.y) + (u.z*u.z + u.w*u.w);
    }
    for (int off = 32; off > 0; off >>= 1) {
        s  += __shfl_down(s, off);
        s2 += __shfl_down(s2, off);
    }
    __shared__ float rs[4], rs2[4];
    int wave = threadIdx.x >> 6, lane = threadIdx.x & 63;
    if (lane == 0) { rs[wave] = s; rs2[wave] = s2; }
    __syncthreads();
    if (threadIdx.x == 0) {
        atomicAdd(&statf[b * 32 + g],       rs[0] + rs[1] + rs[2] + rs[3]);
        atomicAdd(&statf[320 + b * 32 + g], rs2[0] + rs2[1] + rs2[2] + rs2[3]);
    }
}

// Stage one 8KB half-chunk (mbA 4KB + mbY 4KB) into an LDS buffer, 1KB per wave
// (8 waves). waves 0-3 -> mbA quarters; waves 4-7 -> mbY quarters. ONE
// global_load_lds instruction per wave. Dest linear (uniform base + lane*16).
__device__ __forceinline__ void stage_chunk(const ushort* ws, ushort* fg,
                                            int hc, int wv, int lane) {
    const char* g = (const char*)ws + (wv >= 4 ? 65536 : 0) + hc * 4096
                    + (wv & 3) * 1024 + lane * 16;
    char* l = (char*)fg + (wv >= 4 ? 4096 : 0) + (wv & 3) * 1024 + lane * 16;
    __builtin_amdgcn_global_load_lds(
        (const __attribute__((address_space(1))) unsigned int*)g,
        (__attribute__((address_space(3))) unsigned int*)l, 16, 0, 0);
}

__global__ __launch_bounds__(512, 2) void main_mfma(
    const float* __restrict__ x, const ushort* __restrict__ ws,
    const float* __restrict__ phib, const float* __restrict__ gnw,
    const float* __restrict__ gnb, const float* __restrict__ wzb,
    float* __restrict__ out)
{
    const int lane = threadIdx.x & 63, wv = threadIdx.x >> 6;   // wv 0..7
    const int m = lane & 15, q = lane >> 4;
    const int blk = blockIdx.x;                       // 1280 blocks, 128 tokens each
    const int b   = blk >> 7;                         // 128 blocks per image
    const int hw0 = ((blk & 127) << 7) + (wv << 4);   // this wave's 16 tokens

    const ushort* phiA = ws + 65536;
    const ushort* wzA  = ws + 69632;
    const float*  statf = (const float*)(ws + 73728);

    __shared__ ushort Fg[3][4096];                    // staging: 3 x 8KB (shared by 8 waves)
    __shared__ ushort Sl[8][2][16 * ETS];             // E: [wave][parity], 20.5KB
    ushort* Ebuf[2] = { &Sl[wv][0][0], &Sl[wv][1][0] };

    const float* xb = x + (size_t)b * CCH * HWN;

    // prologue: stage chunks 0 and 1 (latency hides under GN+phi).
    stage_chunk(ws, &Fg[0][0], 0, wv, lane);
    stage_chunk(ws, &Fg[1][0], 1, wv, lane);

    // ---- stage 1: x -> GroupNorm (finalize from atomic sums) -> bf16 B-frags ----
    short8 bx[2];
#pragma unroll
    for (int s = 0; s < 2; ++s) {
        const int cbase = s * 32 + q * 8;
        f32x4 sm4 = *(const f32x4*)(statf + b * 32 + (cbase >> 1));
        f32x4 sq4 = *(const f32x4*)(statf + 320 + b * 32 + (cbase >> 1));
        f32x4 mu4, rs4;
#pragma unroll
        for (int r = 0; r < 4; ++r) {
            mu4[r] = sm4[r] * (1.f / 32768.f);
            float var = sq4[r] * (1.f / 32768.f) - mu4[r] * mu4[r];
            rs4[r] = rsqrtf(var + 1e-6f);
        }
        f32x4 gwv0 = *(const f32x4*)(gnw + cbase), gwv1 = *(const f32x4*)(gnw + cbase + 4);
        f32x4 gbv0 = *(const f32x4*)(gnb + cbase), gbv1 = *(const f32x4*)(gnb + cbase + 4);
#pragma unroll
        for (int j = 0; j < 8; ++j) {
            float v  = xb[(size_t)(cbase + j) * HWN + hw0 + m];
            float gw = (j < 4) ? gwv0[j & 3] : gwv1[j & 3];
            float gb = (j < 4) ? gbv0[j & 3] : gbv1[j & 3];
            float xn = (v - mu4[j >> 1]) * rs4[j >> 1] * gw + gb;
            bx[s][j] = (short)f2bf(xn);
        }
    }

    // ---- P^T = phi_w * xn ; channels 0..31 -> Ebuf[0], 32..63 -> Ebuf[1] ----
#pragma unroll
    for (int mt = 0; mt < 4; ++mt) {
        f32x4 a = (f32x4){0.f,0.f,0.f,0.f};
#pragma unroll
        for (int s = 0; s < 2; ++s) {
            short8 ap = *(const short8*)(phiA + (((mt * 2 + s) * 64 + lane) << 3));
            a = __builtin_amdgcn_mfma_f32_16x16x32_bf16(ap, bx[s], a, 0, 0, 0);
        }
        f32x4 pb = *(const f32x4*)(phib + mt * 16 + q * 4);
        *(uint2*)(Ebuf[mt >> 1] + m * ETS + (mt & 1) * 16 + q * 4) =
            make_uint2(pk2((a[0]+pb[0])*PSC, (a[1]+pb[1])*PSC),
                       pk2((a[2]+pb[2])*PSC, (a[3]+pb[3])*PSC));
    }

    // hoist this lane's token-row of P (chunk-invariant score B-frags)
    short8 bp[2];
#pragma unroll
    for (int s = 0; s < 2; ++s)
        bp[s] = *(const short8*)(Ebuf[s] + m * ETS + q * 8);

    // chunk-0 staged data must be resident before anyone reads it.
    asm volatile("s_waitcnt vmcnt(1)" ::: "memory");
    __builtin_amdgcn_s_barrier();

    // ---- streaming softmax + Y over 16 half-chunks of 32 codebook entries ----
    f32x4 accY[4];
#pragma unroll
    for (int mt = 0; mt < 4; ++mt) accY[mt] = (f32x4){0.f,0.f,0.f,0.f};
    float lsum = 0.f;

    ushort* f0 = &Fg[0][0];    // read buffer for current chunk
    ushort* f1 = &Fg[1][0];    // next
    ushort* f2 = &Fg[2][0];    // stage target

    for (int hc = 0; hc < 16; ++hc) {
        if (hc < 14) stage_chunk(ws, f2, hc + 2, wv, lane);
        const ushort* fA = f0;            // mbA half-chunk: 2048 ushorts
        const ushort* fY = f0 + 2048;     // mbY half-chunk: 2048 ushorts
        ushort* Eb = Ebuf[hc & 1];
#pragma unroll
        for (int u = 0; u < 2; ++u) {
            short8 am0 = *(const short8*)(fA + (((u * 2 + 0) * 64 + lane) << 3));
            short8 am1 = *(const short8*)(fA + (((u * 2 + 1) * 64 + lane) << 3));
            f32x4 sa = (f32x4){0.f,0.f,0.f,0.f};
            sa = __builtin_amdgcn_mfma_f32_16x16x32_bf16(am0, bp[0], sa, 0, 0, 0);
            sa = __builtin_amdgcn_mfma_f32_16x16x32_bf16(am1, bp[1], sa, 0, 0, 0);
            float e0 = __builtin_exp2f(sa[0]), e1 = __builtin_exp2f(sa[1]);
            float e2 = __builtin_exp2f(sa[2]), e3 = __builtin_exp2f(sa[3]);
            lsum += (e0 + e1) + (e2 + e3);
            *(uint2*)(Eb + m * ETS + u * 16 + q * 4) =
                make_uint2(pk2(e0, e1), pk2(e2, e3));
        }
        {
            short8 be = *(const short8*)(Eb + m * ETS + q * 8);
#pragma unroll
            for (int mt = 0; mt < 4; ++mt) {
                short8 ay = *(const short8*)(fY + (((mt * 64 + lane)) << 3));
                accY[mt] = __builtin_amdgcn_mfma_f32_16x16x32_bf16(ay, be, accY[mt], 0, 0, 0);
            }
        }
        // counted wait: stage(hc+1) (1 load, second-newest) must be resident for
        // the next chunk; the newest stage (hc+2) stays in flight across the barrier.
        if (hc < 14) {
            asm volatile("s_waitcnt vmcnt(1)" ::: "memory");
            __builtin_amdgcn_s_barrier();
        } else if (hc == 14) {
            asm volatile("s_waitcnt vmcnt(0)" ::: "memory");
            __builtin_amdgcn_s_barrier();
        }
        ushort* t = f0; f0 = f1; f1 = f2; f2 = t;   // rotate triple buffer
    }

    // softmax denominator: lane's C-column IS its token; reduce across q
    float l = lsum;
    l += __shfl_xor(l, 16);
    l += __shfl_xor(l, 32);
    const float linv = 1.f / l;

    // ---- Y -> E (channels 0..31 -> Ebuf[0], 32..63 -> Ebuf[1]), then wz GEMM ----
#pragma unroll
    for (int mt = 0; mt < 4; ++mt)
        *(uint2*)(Ebuf[mt >> 1] + m * ETS + (mt & 1) * 16 + q * 4) =
            make_uint2(pk2(accY[mt][0], accY[mt][1]), pk2(accY[mt][2], accY[mt][3]));

    short8 by[2];
#pragma unroll
    for (int s = 0; s < 2; ++s)
        by[s] = *(const short8*)(Ebuf[s] + m * ETS + q * 8);

    float* ob = out + (size_t)b * CCH * HWN;
#pragma unroll
    for (int mt = 0; mt < 4; ++mt) {
        f32x4 c = (f32x4){0.f,0.f,0.f,0.f};
#pragma unroll
        for (int s = 0; s < 2; ++s) {
            short8 aw = *(const short8*)(wzA + (((mt * 2 + s) * 64 + lane) << 3));
            c = __builtin_amdgcn_mfma_f32_16x16x32_bf16(aw, by[s], c, 0, 0, 0);
        }
        f32x4 wb = *(const f32x4*)(wzb + mt * 16 + q * 4);
#pragma unroll
        for (int r = 0; r < 4; ++r) {
            int o = mt * 16 + q * 4 + r;
            size_t base = (size_t)o * HWN + hw0 + m;
            ob[base] = c[r] * linv + wb[r] + xb[base];
        }
    }
}

extern "C" void kernel_launch(void* const* d_in, const int* in_sizes, int n_in,
                              void* d_out, int out_size, void* d_ws, size_t ws_size,
                              hipStream_t stream) {
    const float* x    = (const float*)d_in[0];
    const float* mb   = (const float*)d_in[1];
    const float* phiw = (const float*)d_in[2];
    const float* phib = (const float*)d_in[3];
    const float* gnw  = (const float*)d_in[4];
    const float* gnb  = (const float*)d_in[5];
    const float* wzw  = (const float*)d_in[6];
    const float* wzb  = (const float*)d_in[7];

    const int B = in_sizes[0] / (CCH * HWN);  // 10
    const int nstat = B * 256;                // 8 partial blocks per (b,g)

    // zero the atomic-sum region (float idx 36864..37504 of ws)
    hipMemsetAsync((char*)d_ws + 36864 * 4, 0, 640 * 4, stream);
    prep_stats_kernel<<<nstat + 288, 256, 0, stream>>>(x, mb, phiw, wzw,
                                                       (ushort*)d_ws, nstat);
    main_mfma<<<B * 128, 512, 0, stream>>>(x, (const ushort*)d_ws,
                                           phib, gnw, gnb, wzb, (float*)d_out);
}

// Round 11
// 149.121 us; speedup vs baseline: 1.0270x; 1.0270x over previous
//
#include <hip/hip_runtime.h>

// GroupNorm(32) -> phi 1x1 -> soft-VQ softmax vs codebook -> wz 1x1 + residual. fp32 I/O.
// x:(10,64,128,128), mb:(64,512), phi_w/wz_w:(64,64). B=10, C=64, HW=16384, K=512.
//
// R20 = R19 resubmitted verbatim (R19's bench failed on container acquisition --
// infrastructure, not kernel: no compile/correctness/hang signal; resource envelope
// is R18-like: 512 thr, 53.2KB LDS, VGPR ~44-52).
//
// R19 design: R18 with the sync cadence halved and the stage pipeline deepened.
// Occupancy theory falsified twice (R17: 16 possible/11.4 measured; R18: 24/11.2):
// residency is pinned ~11 waves/CU; the wins came from per-wave stall reduction.
// Remaining stalls: 17 block-wide 512-thr barriers + 1-chunk stage cover.
//  - 8 intervals of TWO half-chunks each; Fg quad-buffered (4 x 8KB = 32KB).
//    Interval i: stage chunks 2i+2,2i+3 (2 loads/wave) at top; compute 2i, 2i+1
//    (inner bodies identical to R18, E parity hc&1); vmcnt(0)+s_barrier at end.
//    Drain covered by a full interval (~1200cy >> ~400cy L2). Barriers 17 -> 9.
//  - Ledger: only stage loads are in-flight vmem at any barrier; both are needed
//    next interval -> vmcnt(0) exact. Barrier + per-wave wait => all 8 waves'
//    slices resident (each wave waits its OWN loads before the barrier).
//  - LDS 53.2KB (Fg 32K + Sl 20.5K) -> 3 blocks/CU (159.7 <= 160KB).
//  - Math / ws layout / epilogue bit-identical to R18 -> absmax unchanged.
//
// ws (ushort): identical to R11/R17/R18:
//  [0    ..32768) mbA  (((hc*2+u)*2+s)*64+lane)*8+j = mb[s*32+q*8+j][(hc*2+u)*16+m]
//  [32768..65536) mbY  ((hc*4+mt)*64+lane)*8+j      = mb[mt*16+m][hc*32+q*8+j]
//  [65536..69632) phiA ((mt*2+s)*64+lane)*8+j = phi_w[mt*16+m][s*32+q*8+j]
//  [69632..73728) wzA  same for wz_w
//  float view at ushort 73728 (statf): [0..320) sum[b*32+g], [320..640) sumsq (atomic)

#define HWN 16384
#define CCH 64
#define PSC 0.18033688011112042f   // 0.125 * log2(e)
#define ETS 40                     // E row stride (ushorts): 32 entries + 8 pad

using short8 = __attribute__((ext_vector_type(8))) short;
using f32x4  = __attribute__((ext_vector_type(4))) float;

__device__ __forceinline__ ushort f2bf(float f) {
    union { float f; unsigned int i; } v; v.f = f;
    return (ushort)((v.i + 0x8000u) >> 16);   // round-half-up
}
__device__ __forceinline__ unsigned int pk2(float a, float b) {
    union { float f; unsigned int i; } va, vb; va.f = a; vb.f = b;
    return __builtin_amdgcn_perm(vb.i + 0x8000u, va.i + 0x8000u, 0x07060302u);
}

// blocks [0, nstat): GroupNorm partial sums, 8 parts per (b,g), atomicAdd into statf.
// blocks [nstat, nstat+288): weight prep gathers. (unchanged)
__global__ __launch_bounds__(256) void prep_stats_kernel(
    const float* __restrict__ x, const float* __restrict__ mb,
    const float* __restrict__ phiw, const float* __restrict__ wzw,
    ushort* __restrict__ ws, int nstat)
{
    if (blockIdx.x >= nstat) {
        int i = (blockIdx.x - nstat) * 256 + threadIdx.x;   // 0..73727
        int j = i & 7, lane = (i >> 3) & 63, m = lane & 15, q = lane >> 4;
        if (i < 32768) {
            int t = i >> 9, tile = t >> 1, s = t & 1;
            ws[i] = f2bf(mb[(s * 32 + q * 8 + j) * 512 + tile * 16 + m]);
        } else if (i < 65536) {
            int t = (i - 32768) >> 9;
            int mt = t & 3, u2 = t >> 2, s2 = u2 & 1, cc = u2 >> 1;
            ws[i] = f2bf(mb[(mt * 16 + m) * 512 + cc * 64 + s2 * 32 + q * 8 + j]);
        } else if (i < 69632) {
            int t = (i - 65536) >> 9, mt = t >> 1, s = t & 1;
            ws[i] = f2bf(phiw[(mt * 16 + m) * 64 + s * 32 + q * 8 + j]);
        } else {
            int t = (i - 69632) >> 9, mt = t >> 1, s = t & 1;
            ws[i] = f2bf(wzw[(mt * 16 + m) * 64 + s * 32 + q * 8 + j]);
        }
        return;
    }
    float* statf = (float*)(ws + 73728);
    int blk  = blockIdx.x;            // b*256 + g*8 + part
    int b    = blk >> 8;
    int g    = (blk >> 3) & 31;
    int part = blk & 7;
    const float4* b4 = (const float4*)(x + (size_t)b * CCH * HWN + (size_t)(g * 2) * HWN) + part * 1024;
    float s = 0.f, s2 = 0.f;
    for (int i = threadIdx.x; i < 1024; i += 256) {
        float4 u = b4[i];
        s  += (u.x + u.y) + (u.z + u.w);
        s2 += (u.x*u.x + u.y*u.y) + (u.z*u.z + u.w*u.w);
    }
    for (int off = 32; off > 0; off >>= 1) {
        s  += __shfl_down(s, off);
        s2 += __shfl_down(s2, off);
    }
    __shared__ float rs[4], rs2[4];
    int wave = threadIdx.x >> 6, lane = threadIdx.x & 63;
    if (lane == 0) { rs[wave] = s; rs2[wave] = s2; }
    __syncthreads();
    if (threadIdx.x == 0) {
        atomicAdd(&statf[b * 32 + g],       rs[0] + rs[1] + rs[2] + rs[3]);
        atomicAdd(&statf[320 + b * 32 + g], rs2[0] + rs2[1] + rs2[2] + rs2[3]);
    }
}

// Stage one 8KB half-chunk (mbA 4KB + mbY 4KB) into an LDS buffer, 1KB per wave
// (8 waves). waves 0-3 -> mbA quarters; waves 4-7 -> mbY quarters. ONE
// global_load_lds instruction per wave. Dest linear (uniform base + lane*16).
__device__ __forceinline__ void stage_chunk(const ushort* ws, ushort* fg,
                                            int hc, int wv, int lane) {
    const char* g = (const char*)ws + (wv >= 4 ? 65536 : 0) + hc * 4096
                    + (wv & 3) * 1024 + lane * 16;
    char* l = (char*)fg + (wv >= 4 ? 4096 : 0) + (wv & 3) * 1024 + lane * 16;
    __builtin_amdgcn_global_load_lds(
        (const __attribute__((address_space(1))) unsigned int*)g,
        (__attribute__((address_space(3))) unsigned int*)l, 16, 0, 0);
}

__global__ __launch_bounds__(512, 2) void main_mfma(
    const float* __restrict__ x, const ushort* __restrict__ ws,
    const float* __restrict__ phib, const float* __restrict__ gnw,
    const float* __restrict__ gnb, const float* __restrict__ wzb,
    float* __restrict__ out)
{
    const int lane = threadIdx.x & 63, wv = threadIdx.x >> 6;   // wv 0..7
    const int m = lane & 15, q = lane >> 4;
    const int blk = blockIdx.x;                       // 1280 blocks, 128 tokens each
    const int b   = blk >> 7;                         // 128 blocks per image
    const int hw0 = ((blk & 127) << 7) + (wv << 4);   // this wave's 16 tokens

    const ushort* phiA = ws + 65536;
    const ushort* wzA  = ws + 69632;
    const float*  statf = (const float*)(ws + 73728);

    __shared__ ushort Fg[4][4096];                    // staging: 4 x 8KB (quad buffer)
    __shared__ ushort Sl[8][2][16 * ETS];             // E: [wave][parity], 20.5KB
    ushort* Ebuf[2] = { &Sl[wv][0][0], &Sl[wv][1][0] };

    const float* xb = x + (size_t)b * CCH * HWN;

    // prologue: stage chunks 0 and 1 (latency hides under GN+phi).
    stage_chunk(ws, &Fg[0][0], 0, wv, lane);
    stage_chunk(ws, &Fg[1][0], 1, wv, lane);

    // ---- stage 1: x -> GroupNorm (finalize from atomic sums) -> bf16 B-frags ----
    short8 bx[2];
#pragma unroll
    for (int s = 0; s < 2; ++s) {
        const int cbase = s * 32 + q * 8;
        f32x4 sm4 = *(const f32x4*)(statf + b * 32 + (cbase >> 1));
        f32x4 sq4 = *(const f32x4*)(statf + 320 + b * 32 + (cbase >> 1));
        f32x4 mu4, rs4;
#pragma unroll
        for (int r = 0; r < 4; ++r) {
            mu4[r] = sm4[r] * (1.f / 32768.f);
            float var = sq4[r] * (1.f / 32768.f) - mu4[r] * mu4[r];
            rs4[r] = rsqrtf(var + 1e-6f);
        }
        f32x4 gwv0 = *(const f32x4*)(gnw + cbase), gwv1 = *(const f32x4*)(gnw + cbase + 4);
        f32x4 gbv0 = *(const f32x4*)(gnb + cbase), gbv1 = *(const f32x4*)(gnb + cbase + 4);
#pragma unroll
        for (int j = 0; j < 8; ++j) {
            float v  = xb[(size_t)(cbase + j) * HWN + hw0 + m];
            float gw = (j < 4) ? gwv0[j & 3] : gwv1[j & 3];
            float gb = (j < 4) ? gbv0[j & 3] : gbv1[j & 3];
            float xn = (v - mu4[j >> 1]) * rs4[j >> 1] * gw + gb;
            bx[s][j] = (short)f2bf(xn);
        }
    }

    // ---- P^T = phi_w * xn ; channels 0..31 -> Ebuf[0], 32..63 -> Ebuf[1] ----
#pragma unroll
    for (int mt = 0; mt < 4; ++mt) {
        f32x4 a = (f32x4){0.f,0.f,0.f,0.f};
#pragma unroll
        for (int s = 0; s < 2; ++s) {
            short8 ap = *(const short8*)(phiA + (((mt * 2 + s) * 64 + lane) << 3));
            a = __builtin_amdgcn_mfma_f32_16x16x32_bf16(ap, bx[s], a, 0, 0, 0);
        }
        f32x4 pb = *(const f32x4*)(phib + mt * 16 + q * 4);
        *(uint2*)(Ebuf[mt >> 1] + m * ETS + (mt & 1) * 16 + q * 4) =
            make_uint2(pk2((a[0]+pb[0])*PSC, (a[1]+pb[1])*PSC),
                       pk2((a[2]+pb[2])*PSC, (a[3]+pb[3])*PSC));
    }

    // hoist this lane's token-row of P (chunk-invariant score B-frags)
    short8 bp[2];
#pragma unroll
    for (int s = 0; s < 2; ++s)
        bp[s] = *(const short8*)(Ebuf[s] + m * ETS + q * 8);

    // chunks 0 AND 1 must be resident (interval 0 reads both).
    asm volatile("s_waitcnt vmcnt(0)" ::: "memory");
    __builtin_amdgcn_s_barrier();

    // ---- streaming softmax + Y: 8 intervals x 2 half-chunks of 32 entries ----
    f32x4 accY[4];
#pragma unroll
    for (int mt = 0; mt < 4; ++mt) accY[mt] = (f32x4){0.f,0.f,0.f,0.f};
    float lsum = 0.f;

    for (int iv = 0; iv < 8; ++iv) {
        if (iv < 7) {                               // stage next interval's pair
            stage_chunk(ws, &Fg[(2 * iv + 2) & 3][0], 2 * iv + 2, wv, lane);
            stage_chunk(ws, &Fg[(2 * iv + 3) & 3][0], 2 * iv + 3, wv, lane);
        }
#pragma unroll
        for (int h = 0; h < 2; ++h) {               // two half-chunks, parity h
            const int hc = 2 * iv + h;
            const ushort* fA = &Fg[hc & 3][0];      // mbA half: 2048 ushorts
            const ushort* fY = fA + 2048;           // mbY half: 2048 ushorts
            ushort* Eb = Ebuf[h];
#pragma unroll
            for (int u = 0; u < 2; ++u) {
                short8 am0 = *(const short8*)(fA + (((u * 2 + 0) * 64 + lane) << 3));
                short8 am1 = *(const short8*)(fA + (((u * 2 + 1) * 64 + lane) << 3));
                f32x4 sa = (f32x4){0.f,0.f,0.f,0.f};
                sa = __builtin_amdgcn_mfma_f32_16x16x32_bf16(am0, bp[0], sa, 0, 0, 0);
                sa = __builtin_amdgcn_mfma_f32_16x16x32_bf16(am1, bp[1], sa, 0, 0, 0);
                float e0 = __builtin_exp2f(sa[0]), e1 = __builtin_exp2f(sa[1]);
                float e2 = __builtin_exp2f(sa[2]), e3 = __builtin_exp2f(sa[3]);
                lsum += (e0 + e1) + (e2 + e3);
                *(uint2*)(Eb + m * ETS + u * 16 + q * 4) =
                    make_uint2(pk2(e0, e1), pk2(e2, e3));
            }
            short8 be = *(const short8*)(Eb + m * ETS + q * 8);
#pragma unroll
            for (int mt = 0; mt < 4; ++mt) {
                short8 ay = *(const short8*)(fY + ((mt * 64 + lane) << 3));
                accY[mt] = __builtin_amdgcn_mfma_f32_16x16x32_bf16(ay, be, accY[mt], 0, 0, 0);
            }
        }
        // next interval reads the pair staged above; drain is covered by this
        // interval's full compute (~1200cy >> L2 latency). No barrier after last.
        if (iv < 7) {
            asm volatile("s_waitcnt vmcnt(0)" ::: "memory");
            __builtin_amdgcn_s_barrier();
        }
    }

    // softmax denominator: lane's C-column IS its token; reduce across q
    float l = lsum;
    l += __shfl_xor(l, 16);
    l += __shfl_xor(l, 32);
    const float linv = 1.f / l;

    // ---- Y -> E (channels 0..31 -> Ebuf[0], 32..63 -> Ebuf[1]), then wz GEMM ----
#pragma unroll
    for (int mt = 0; mt < 4; ++mt)
        *(uint2*)(Ebuf[mt >> 1] + m * ETS + (mt & 1) * 16 + q * 4) =
            make_uint2(pk2(accY[mt][0], accY[mt][1]), pk2(accY[mt][2], accY[mt][3]));

    short8 by[2];
#pragma unroll
    for (int s = 0; s < 2; ++s)
        by[s] = *(const short8*)(Ebuf[s] + m * ETS + q * 8);

    float* ob = out + (size_t)b * CCH * HWN;
#pragma unroll
    for (int mt = 0; mt < 4; ++mt) {
        f32x4 c = (f32x4){0.f,0.f,0.f,0.f};
#pragma unroll
        for (int s = 0; s < 2; ++s) {
            short8 aw = *(const short8*)(wzA + (((mt * 2 + s) * 64 + lane) << 3));
            c = __builtin_amdgcn_mfma_f32_16x16x32_bf16(aw, by[s], c, 0, 0, 0);
        }
        f32x4 wb = *(const f32x4*)(wzb + mt * 16 + q * 4);
#pragma unroll
        for (int r = 0; r < 4; ++r) {
            int o = mt * 16 + q * 4 + r;
            size_t base = (size_t)o * HWN + hw0 + m;
            ob[base] = c[r] * linv + wb[r] + xb[base];
        }
    }
}

extern "C" void kernel_launch(void* const* d_in, const int* in_sizes, int n_in,
                              void* d_out, int out_size, void* d_ws, size_t ws_size,
                              hipStream_t stream) {
    const float* x    = (const float*)d_in[0];
    const float* mb   = (const float*)d_in[1];
    const float* phiw = (const float*)d_in[2];
    const float* phib = (const float*)d_in[3];
    const float* gnw  = (const float*)d_in[4];
    const float* gnb  = (const float*)d_in[5];
    const float* wzw  = (const float*)d_in[6];
    const float* wzb  = (const float*)d_in[7];

    const int B = in_sizes[0] / (CCH * HWN);  // 10
    const int nstat = B * 256;                // 8 partial blocks per (b,g)

    // zero the atomic-sum region (float idx 36864..37504 of ws)
    hipMemsetAsync((char*)d_ws + 36864 * 4, 0, 640 * 4, stream);
    prep_stats_kernel<<<nstat + 288, 256, 0, stream>>>(x, mb, phiw, wzw,
                                                       (ushort*)d_ws, nstat);
    main_mfma<<<B * 128, 512, 0, stream>>>(x, (const ushort*)d_ws,
                                           phib, gnw, gnb, wzb, (float*)d_out);
}

// Round 12
// 148.666 us; speedup vs baseline: 1.0302x; 1.0031x over previous
//
#include <hip/hip_runtime.h>

// GroupNorm(32) -> phi 1x1 -> soft-VQ softmax vs codebook -> wz 1x1 + residual. fp32 I/O.
// x:(10,64,128,128), mb:(64,512), phi_w/wz_w:(64,64). B=10, C=64, HW=16384, K=512.
//
// R21 = R19/R20 (54.6us main) with each interval split into phases:
//   phase A: scores+exp+E-write for BOTH half-chunks (E[0] then E[1])
//   phase B: Y-MFMA for both (be read E[0] ~800cy after its write -> DS latency
//            hidden under scores(h1); 8 Y-MFMAs cluster -> setprio has a phase
//            split to arbitrate, T5 prerequisite now satisfied)
// DS ops are in-order per wave and E is per-wave -> data correct; accY/lsum
// accumulation order unchanged -> bit-identical output.
// Everything else identical to R20: quad-buffered Fg, 8 intervals, counted
// vmcnt(0)+s_barrier only at interval ends (9 barriers), 512-thr blocks.
//
// ws (ushort): identical to R11/R17/R18/R19:
//  [0    ..32768) mbA  (((hc*2+u)*2+s)*64+lane)*8+j = mb[s*32+q*8+j][(hc*2+u)*16+m]
//  [32768..65536) mbY  ((hc*4+mt)*64+lane)*8+j      = mb[mt*16+m][hc*32+q*8+j]
//  [65536..69632) phiA ((mt*2+s)*64+lane)*8+j = phi_w[mt*16+m][s*32+q*8+j]
//  [69632..73728) wzA  same for wz_w
//  float view at ushort 73728 (statf): [0..320) sum[b*32+g], [320..640) sumsq (atomic)

#define HWN 16384
#define CCH 64
#define PSC 0.18033688011112042f   // 0.125 * log2(e)
#define ETS 40                     // E row stride (ushorts): 32 entries + 8 pad

using short8 = __attribute__((ext_vector_type(8))) short;
using f32x4  = __attribute__((ext_vector_type(4))) float;

__device__ __forceinline__ ushort f2bf(float f) {
    union { float f; unsigned int i; } v; v.f = f;
    return (ushort)((v.i + 0x8000u) >> 16);   // round-half-up
}
__device__ __forceinline__ unsigned int pk2(float a, float b) {
    union { float f; unsigned int i; } va, vb; va.f = a; vb.f = b;
    return __builtin_amdgcn_perm(vb.i + 0x8000u, va.i + 0x8000u, 0x07060302u);
}

// blocks [0, nstat): GroupNorm partial sums, 8 parts per (b,g), atomicAdd into statf.
// blocks [nstat, nstat+288): weight prep gathers. (unchanged)
__global__ __launch_bounds__(256) void prep_stats_kernel(
    const float* __restrict__ x, const float* __restrict__ mb,
    const float* __restrict__ phiw, const float* __restrict__ wzw,
    ushort* __restrict__ ws, int nstat)
{
    if (blockIdx.x >= nstat) {
        int i = (blockIdx.x - nstat) * 256 + threadIdx.x;   // 0..73727
        int j = i & 7, lane = (i >> 3) & 63, m = lane & 15, q = lane >> 4;
        if (i < 32768) {
            int t = i >> 9, tile = t >> 1, s = t & 1;
            ws[i] = f2bf(mb[(s * 32 + q * 8 + j) * 512 + tile * 16 + m]);
        } else if (i < 65536) {
            int t = (i - 32768) >> 9;
            int mt = t & 3, u2 = t >> 2, s2 = u2 & 1, cc = u2 >> 1;
            ws[i] = f2bf(mb[(mt * 16 + m) * 512 + cc * 64 + s2 * 32 + q * 8 + j]);
        } else if (i < 69632) {
            int t = (i - 65536) >> 9, mt = t >> 1, s = t & 1;
            ws[i] = f2bf(phiw[(mt * 16 + m) * 64 + s * 32 + q * 8 + j]);
        } else {
            int t = (i - 69632) >> 9, mt = t >> 1, s = t & 1;
            ws[i] = f2bf(wzw[(mt * 16 + m) * 64 + s * 32 + q * 8 + j]);
        }
        return;
    }
    float* statf = (float*)(ws + 73728);
    int blk  = blockIdx.x;            // b*256 + g*8 + part
    int b    = blk >> 8;
    int g    = (blk >> 3) & 31;
    int part = blk & 7;
    const float4* b4 = (const float4*)(x + (size_t)b * CCH * HWN + (size_t)(g * 2) * HWN) + part * 1024;
    float s = 0.f, s2 = 0.f;
    for (int i = threadIdx.x; i < 1024; i += 256) {
        float4 u = b4[i];
        s  += (u.x + u.y) + (u.z + u.w);
        s2 += (u.x*u.x + u.y*u.y) + (u.z*u.z + u.w*u.w);
    }
    for (int off = 32; off > 0; off >>= 1) {
        s  += __shfl_down(s, off);
        s2 += __shfl_down(s2, off);
    }
    __shared__ float rs[4], rs2[4];
    int wave = threadIdx.x >> 6, lane = threadIdx.x & 63;
    if (lane == 0) { rs[wave] = s; rs2[wave] = s2; }
    __syncthreads();
    if (threadIdx.x == 0) {
        atomicAdd(&statf[b * 32 + g],       rs[0] + rs[1] + rs[2] + rs[3]);
        atomicAdd(&statf[320 + b * 32 + g], rs2[0] + rs2[1] + rs2[2] + rs2[3]);
    }
}

// Stage one 8KB half-chunk (mbA 4KB + mbY 4KB) into an LDS buffer, 1KB per wave
// (8 waves). waves 0-3 -> mbA quarters; waves 4-7 -> mbY quarters. ONE
// global_load_lds instruction per wave. Dest linear (uniform base + lane*16).
__device__ __forceinline__ void stage_chunk(const ushort* ws, ushort* fg,
                                            int hc, int wv, int lane) {
    const char* g = (const char*)ws + (wv >= 4 ? 65536 : 0) + hc * 4096
                    + (wv & 3) * 1024 + lane * 16;
    char* l = (char*)fg + (wv >= 4 ? 4096 : 0) + (wv & 3) * 1024 + lane * 16;
    __builtin_amdgcn_global_load_lds(
        (const __attribute__((address_space(1))) unsigned int*)g,
        (__attribute__((address_space(3))) unsigned int*)l, 16, 0, 0);
}

__global__ __launch_bounds__(512, 2) void main_mfma(
    const float* __restrict__ x, const ushort* __restrict__ ws,
    const float* __restrict__ phib, const float* __restrict__ gnw,
    const float* __restrict__ gnb, const float* __restrict__ wzb,
    float* __restrict__ out)
{
    const int lane = threadIdx.x & 63, wv = threadIdx.x >> 6;   // wv 0..7
    const int m = lane & 15, q = lane >> 4;
    const int blk = blockIdx.x;                       // 1280 blocks, 128 tokens each
    const int b   = blk >> 7;                         // 128 blocks per image
    const int hw0 = ((blk & 127) << 7) + (wv << 4);   // this wave's 16 tokens

    const ushort* phiA = ws + 65536;
    const ushort* wzA  = ws + 69632;
    const float*  statf = (const float*)(ws + 73728);

    __shared__ ushort Fg[4][4096];                    // staging: 4 x 8KB (quad buffer)
    __shared__ ushort Sl[8][2][16 * ETS];             // E: [wave][parity], 20.5KB
    ushort* Ebuf[2] = { &Sl[wv][0][0], &Sl[wv][1][0] };

    const float* xb = x + (size_t)b * CCH * HWN;

    // prologue: stage chunks 0 and 1 (latency hides under GN+phi).
    stage_chunk(ws, &Fg[0][0], 0, wv, lane);
    stage_chunk(ws, &Fg[1][0], 1, wv, lane);

    // ---- stage 1: x -> GroupNorm (finalize from atomic sums) -> bf16 B-frags ----
    short8 bx[2];
#pragma unroll
    for (int s = 0; s < 2; ++s) {
        const int cbase = s * 32 + q * 8;
        f32x4 sm4 = *(const f32x4*)(statf + b * 32 + (cbase >> 1));
        f32x4 sq4 = *(const f32x4*)(statf + 320 + b * 32 + (cbase >> 1));
        f32x4 mu4, rs4;
#pragma unroll
        for (int r = 0; r < 4; ++r) {
            mu4[r] = sm4[r] * (1.f / 32768.f);
            float var = sq4[r] * (1.f / 32768.f) - mu4[r] * mu4[r];
            rs4[r] = rsqrtf(var + 1e-6f);
        }
        f32x4 gwv0 = *(const f32x4*)(gnw + cbase), gwv1 = *(const f32x4*)(gnw + cbase + 4);
        f32x4 gbv0 = *(const f32x4*)(gnb + cbase), gbv1 = *(const f32x4*)(gnb + cbase + 4);
#pragma unroll
        for (int j = 0; j < 8; ++j) {
            float v  = xb[(size_t)(cbase + j) * HWN + hw0 + m];
            float gw = (j < 4) ? gwv0[j & 3] : gwv1[j & 3];
            float gb = (j < 4) ? gbv0[j & 3] : gbv1[j & 3];
            float xn = (v - mu4[j >> 1]) * rs4[j >> 1] * gw + gb;
            bx[s][j] = (short)f2bf(xn);
        }
    }

    // ---- P^T = phi_w * xn ; channels 0..31 -> Ebuf[0], 32..63 -> Ebuf[1] ----
#pragma unroll
    for (int mt = 0; mt < 4; ++mt) {
        f32x4 a = (f32x4){0.f,0.f,0.f,0.f};
#pragma unroll
        for (int s = 0; s < 2; ++s) {
            short8 ap = *(const short8*)(phiA + (((mt * 2 + s) * 64 + lane) << 3));
            a = __builtin_amdgcn_mfma_f32_16x16x32_bf16(ap, bx[s], a, 0, 0, 0);
        }
        f32x4 pb = *(const f32x4*)(phib + mt * 16 + q * 4);
        *(uint2*)(Ebuf[mt >> 1] + m * ETS + (mt & 1) * 16 + q * 4) =
            make_uint2(pk2((a[0]+pb[0])*PSC, (a[1]+pb[1])*PSC),
                       pk2((a[2]+pb[2])*PSC, (a[3]+pb[3])*PSC));
    }

    // hoist this lane's token-row of P (chunk-invariant score B-frags)
    short8 bp[2];
#pragma unroll
    for (int s = 0; s < 2; ++s)
        bp[s] = *(const short8*)(Ebuf[s] + m * ETS + q * 8);

    // chunks 0 AND 1 must be resident (interval 0 reads both).
    asm volatile("s_waitcnt vmcnt(0)" ::: "memory");
    __builtin_amdgcn_s_barrier();

    // ---- streaming softmax + Y: 8 intervals x 2 half-chunks of 32 entries ----
    f32x4 accY[4];
#pragma unroll
    for (int mt = 0; mt < 4; ++mt) accY[mt] = (f32x4){0.f,0.f,0.f,0.f};
    float lsum = 0.f;

    for (int iv = 0; iv < 8; ++iv) {
        if (iv < 7) {                               // stage next interval's pair
            stage_chunk(ws, &Fg[(2 * iv + 2) & 3][0], 2 * iv + 2, wv, lane);
            stage_chunk(ws, &Fg[(2 * iv + 3) & 3][0], 2 * iv + 3, wv, lane);
        }
        // ---- phase A: scores + exp + E-write for both half-chunks ----
#pragma unroll
        for (int h = 0; h < 2; ++h) {
            const int hc = 2 * iv + h;
            const ushort* fA = &Fg[hc & 3][0];      // mbA half: 2048 ushorts
            ushort* Eb = Ebuf[h];
#pragma unroll
            for (int u = 0; u < 2; ++u) {
                short8 am0 = *(const short8*)(fA + (((u * 2 + 0) * 64 + lane) << 3));
                short8 am1 = *(const short8*)(fA + (((u * 2 + 1) * 64 + lane) << 3));
                f32x4 sa = (f32x4){0.f,0.f,0.f,0.f};
                sa = __builtin_amdgcn_mfma_f32_16x16x32_bf16(am0, bp[0], sa, 0, 0, 0);
                sa = __builtin_amdgcn_mfma_f32_16x16x32_bf16(am1, bp[1], sa, 0, 0, 0);
                float e0 = __builtin_exp2f(sa[0]), e1 = __builtin_exp2f(sa[1]);
                float e2 = __builtin_exp2f(sa[2]), e3 = __builtin_exp2f(sa[3]);
                lsum += (e0 + e1) + (e2 + e3);
                *(uint2*)(Eb + m * ETS + u * 16 + q * 4) =
                    make_uint2(pk2(e0, e1), pk2(e2, e3));
            }
        }
        // ---- phase B: Y-MFMA cluster for both half-chunks ----
        // be(h0) read lands ~800cy after its E-write (hidden under scores(h1));
        // 8 MFMAs cluster under setprio(1) (T5: phase-split prerequisite now met).
        __builtin_amdgcn_s_setprio(1);
#pragma unroll
        for (int h = 0; h < 2; ++h) {
            const int hc = 2 * iv + h;
            const ushort* fY = &Fg[hc & 3][0] + 2048;   // mbY half: 2048 ushorts
            short8 be = *(const short8*)(Ebuf[h] + m * ETS + q * 8);
#pragma unroll
            for (int mt = 0; mt < 4; ++mt) {
                short8 ay = *(const short8*)(fY + ((mt * 64 + lane) << 3));
                accY[mt] = __builtin_amdgcn_mfma_f32_16x16x32_bf16(ay, be, accY[mt], 0, 0, 0);
            }
        }
        __builtin_amdgcn_s_setprio(0);
        // next interval reads the pair staged above; drain covered by this
        // interval's full compute. No barrier after the last interval.
        if (iv < 7) {
            asm volatile("s_waitcnt vmcnt(0)" ::: "memory");
            __builtin_amdgcn_s_barrier();
        }
    }

    // softmax denominator: lane's C-column IS its token; reduce across q
    float l = lsum;
    l += __shfl_xor(l, 16);
    l += __shfl_xor(l, 32);
    const float linv = 1.f / l;

    // ---- Y -> E (channels 0..31 -> Ebuf[0], 32..63 -> Ebuf[1]), then wz GEMM ----
#pragma unroll
    for (int mt = 0; mt < 4; ++mt)
        *(uint2*)(Ebuf[mt >> 1] + m * ETS + (mt & 1) * 16 + q * 4) =
            make_uint2(pk2(accY[mt][0], accY[mt][1]), pk2(accY[mt][2], accY[mt][3]));

    short8 by[2];
#pragma unroll
    for (int s = 0; s < 2; ++s)
        by[s] = *(const short8*)(Ebuf[s] + m * ETS + q * 8);

    float* ob = out + (size_t)b * CCH * HWN;
#pragma unroll
    for (int mt = 0; mt < 4; ++mt) {
        f32x4 c = (f32x4){0.f,0.f,0.f,0.f};
#pragma unroll
        for (int s = 0; s < 2; ++s) {
            short8 aw = *(const short8*)(wzA + (((mt * 2 + s) * 64 + lane) << 3));
            c = __builtin_amdgcn_mfma_f32_16x16x32_bf16(aw, by[s], c, 0, 0, 0);
        }
        f32x4 wb = *(const f32x4*)(wzb + mt * 16 + q * 4);
#pragma unroll
        for (int r = 0; r < 4; ++r) {
            int o = mt * 16 + q * 4 + r;
            size_t base = (size_t)o * HWN + hw0 + m;
            ob[base] = c[r] * linv + wb[r] + xb[base];
        }
    }
}

extern "C" void kernel_launch(void* const* d_in, const int* in_sizes, int n_in,
                              void* d_out, int out_size, void* d_ws, size_t ws_size,
                              hipStream_t stream) {
    const float* x    = (const float*)d_in[0];
    const float* mb   = (const float*)d_in[1];
    const float* phiw = (const float*)d_in[2];
    const float* phib = (const float*)d_in[3];
    const float* gnw  = (const float*)d_in[4];
    const float* gnb  = (const float*)d_in[5];
    const float* wzw  = (const float*)d_in[6];
    const float* wzb  = (const float*)d_in[7];

    const int B = in_sizes[0] / (CCH * HWN);  // 10
    const int nstat = B * 256;                // 8 partial blocks per (b,g)

    // zero the atomic-sum region (float idx 36864..37504 of ws)
    hipMemsetAsync((char*)d_ws + 36864 * 4, 0, 640 * 4, stream);
    prep_stats_kernel<<<nstat + 288, 256, 0, stream>>>(x, mb, phiw, wzw,
                                                       (ushort*)d_ws, nstat);
    main_mfma<<<B * 128, 512, 0, stream>>>(x, (const ushort*)d_ws,
                                           phib, gnw, gnb, wzb, (float*)d_out);
}